// Round 6
// baseline (211.744 us; speedup 1.0000x reference)
//
#include <hip/hip_runtime.h>
#include <cstdint>

#define DEV static __device__ __forceinline__
#define WAITVM(N) asm volatile("s_waitcnt vmcnt(" #N ")" ::: "memory")

typedef float f32x4 __attribute__((ext_vector_type(4)));
typedef short bf16x8 __attribute__((ext_vector_type(8)));   // 8 bf16 in 4 VGPRs

constexpr int Bsz = 16384;
constexpr int Dd  = 1024;   // D
constexpr int DKd = 1024;   // DK

// float -> bf16 bits, round-to-nearest-even
DEV unsigned short f2bf(float f) {
    uint32_t u = __builtin_bit_cast(uint32_t, f);
    u += 0x7FFFu + ((u >> 16) & 1u);
    return (unsigned short)(u >> 16);
}

// async global->LDS, 16 bytes per lane (dest must be linear: base + lane*16)
DEV void async_lds16(const void* g, void* l) {
    __builtin_amdgcn_global_load_lds(
        (const __attribute__((address_space(1))) void*)g,
        (__attribute__((address_space(3))) void*)l,
        16, 0, 0);
}

// ---------------- prep (single kernel): mixed = bf16(mix*x + (1-mix)*x_prev),
// WkB = bf16(Wk), WfB = bf16(Wf) ----------------
__global__ void k_prep(const float4* __restrict__ x, const float4* __restrict__ xp,
                       const float* __restrict__ mixp,
                       const float4* __restrict__ Wk, const float4* __restrict__ Wf,
                       unsigned short* __restrict__ mixed,
                       unsigned short* __restrict__ WkB,
                       unsigned short* __restrict__ WfB) {
    constexpr int n_mix = Bsz * Dd / 4;       // 4194304
    constexpr int n_w   = DKd * Dd / 4;       // 262144
    constexpr int total = n_mix + 2 * n_w;
    const float m = *mixp, m1 = 1.0f - m;
    int i = blockIdx.x * blockDim.x + threadIdx.x;
    const int st = gridDim.x * blockDim.x;
    for (; i < total; i += st) {
        float4 a;
        unsigned short* dst;
        int idx;
        if (i < n_mix) {
            float4 xa = x[i], xb = xp[i];
            a.x = m * xa.x + m1 * xb.x;
            a.y = m * xa.y + m1 * xb.y;
            a.z = m * xa.z + m1 * xb.z;
            a.w = m * xa.w + m1 * xb.w;
            dst = mixed; idx = i;
        } else if (i < n_mix + n_w) {
            a = Wk[i - n_mix]; dst = WkB; idx = i - n_mix;
        } else {
            a = Wf[i - n_mix - n_w]; dst = WfB; idx = i - n_mix - n_w;
        }
        ushort4 o;
        o.x = f2bf(a.x); o.y = f2bf(a.y); o.z = f2bf(a.z); o.w = f2bf(a.w);
        reinterpret_cast<ushort4*>(dst)[idx] = o;
    }
}

// ---- NT GEMM, counted-vmcnt 4-phase pipeline ----
// C[M,N] = A[M,1024] * Bw[N,1024]^T. 128x128 tile, BK=64 as 2 kk-chunks of 32.
// LDS [2buf][2kk][128][32] per operand (64 KB total) -> 2 blocks/CU.
// Phase = {ds_read frags, 16 MFMA (setprio), vmcnt(8), barrier, stage chunk t+2}.
// 3 chunks (12 loads/thread) in flight; vmcnt never 0 until the tail.
// EPI==1: RWKV epilogue; EPI==0: bias epilogue.
template <int EPI>
__global__ __launch_bounds__(256, 2)
void k_gemm(const unsigned short* __restrict__ A,   // [M,1024] bf16
            const unsigned short* __restrict__ Bw,  // [N,1024] bf16
            const float* __restrict__ bias,
            const float* __restrict__ num, const float* __restrict__ den,
            const float* __restrict__ bonus, const float* __restrict__ decayp,
            float* __restrict__ o0, float* __restrict__ o1,
            unsigned short* __restrict__ orw)
{
    __shared__ __align__(16) unsigned short As[2][2][128 * 32];  // 32 KB
    __shared__ __align__(16) unsigned short Bs[2][2][128 * 32];  // 32 KB

    const int tid = threadIdx.x;
    // grid = 1024: 128 row-blocks x 8 col-blocks; col-block == XCD (bid&7):
    // each XCD keeps one 256 KB B-panel L2-resident and streams A.
    const int bid = (int)blockIdx.x;
    const int cb  = bid & 7;
    const int rb  = bid >> 3;
    const int row0 = rb * 128;
    const int col0 = cb * 128;

    const int lane = tid & 63;
    const int wid  = tid >> 6;                      // 0..3
    const int wr = wid >> 1, wc = wid & 1;          // 2x2 wave grid: 64x64 per wave
    const int l16 = lane & 15, lq = lane >> 4;

    // ---- staging addressing (hoisted). seg s in [0,512): r=s>>2, gphys=s&3.
    // source pre-swizzled: glog = gphys ^ ((r>>1)&3); LDS dest linear (rule #21).
    const int r1   = tid >> 2;                      // 0..63 (seg tid); seg tid+256 -> r1+64
    const int glog = (tid & 3) ^ ((tid >> 3) & 3);
    const unsigned short* pa0 = A  + (size_t)(row0 + r1) * 1024 + glog * 8;
    const unsigned short* pa1 = A  + (size_t)(row0 + r1 + 64) * 1024 + glog * 8;
    const unsigned short* pb0 = Bw + (size_t)(col0 + r1) * 1024 + glog * 8;
    const unsigned short* pb1 = Bw + (size_t)(col0 + r1 + 64) * 1024 + glog * 8;

    // ---- ds_read offsets: row = (wr|wc)*64 + m*16 + l16, phys grp = lq ^ ((l16>>1)&3)
    const int swz   = (l16 >> 1) & 3;
    const int abase = (wr * 64 + l16) * 32 + ((lq ^ swz) << 3);   // + m*512
    const int bbase = (wc * 64 + l16) * 32 + ((lq ^ swz) << 3);   // + n*512

    f32x4 acc[4][4] = {};

    auto stage = [&](int buf, int kk, int t) {
        const int off = t * 64 + kk * 32;           // shorts along K
        async_lds16(pa0 + off, &As[buf][kk][tid * 8]);
        async_lds16(pa1 + off, &As[buf][kk][(tid + 256) * 8]);
        async_lds16(pb0 + off, &Bs[buf][kk][tid * 8]);
        async_lds16(pb1 + off, &Bs[buf][kk][(tid + 256) * 8]);
    };

    auto compute = [&](int buf, int kk) {
        const unsigned short* Ar = &As[buf][kk][abase];
        const unsigned short* Br = &Bs[buf][kk][bbase];
        bf16x8 af[4], bfr[4];
#pragma unroll
        for (int n = 0; n < 4; ++n)
            bfr[n] = *reinterpret_cast<const bf16x8*>(Br + n * 512);
#pragma unroll
        for (int m = 0; m < 4; ++m)
            af[m] = *reinterpret_cast<const bf16x8*>(Ar + m * 512);
        __builtin_amdgcn_s_setprio(1);
#pragma unroll
        for (int m = 0; m < 4; ++m)
#pragma unroll
            for (int n = 0; n < 4; ++n)
                acc[m][n] = __builtin_amdgcn_mfma_f32_16x16x32_bf16(
                    af[m], bfr[n], acc[m][n], 0, 0, 0);
        __builtin_amdgcn_s_setprio(0);
    };

    // prologue: chunks C0(0),C1(0),C0(1),C1(1) in flight (16 loads)
    stage(0, 0, 0); stage(0, 1, 0); stage(1, 0, 1); stage(1, 1, 1);
    WAITVM(12);                                     // C0(0) resident
    __builtin_amdgcn_s_barrier();
    __builtin_amdgcn_sched_barrier(0);

#pragma unroll 1
    for (int t = 0; t < 14; ++t) {
        const int buf = t & 1;
        compute(buf, 0);
        WAITVM(8);                                  // C1(t) resident
        __builtin_amdgcn_s_barrier();
        __builtin_amdgcn_sched_barrier(0);
        stage(buf, 0, t + 2);                       // overwrite just-consumed region
        compute(buf, 1);
        WAITVM(8);                                  // C0(t+1) resident
        __builtin_amdgcn_s_barrier();
        __builtin_amdgcn_sched_barrier(0);
        stage(buf, 1, t + 2);
    }
    // t = 14 (no more staging)
    compute(0, 0);
    WAITVM(8);  __builtin_amdgcn_s_barrier(); __builtin_amdgcn_sched_barrier(0);
    compute(0, 1);
    WAITVM(4);  __builtin_amdgcn_s_barrier(); __builtin_amdgcn_sched_barrier(0);
    // t = 15
    compute(1, 0);
    WAITVM(0);  __builtin_amdgcn_s_barrier(); __builtin_amdgcn_sched_barrier(0);
    compute(1, 1);

    // ---------------- epilogue ----------------
    // C/D layout: col = lane&15, row = (lane>>4)*4 + reg  (guide §3, m89-verified)
    const int baserow = row0 + wr * 64 + lq * 4;
    const int basecol = col0 + wc * 64 + l16;

    if constexpr (EPI == 1) {
        const float w_decay = __expf(-__expf(*decayp));
        float cbias[4], cebon[4];
#pragma unroll
        for (int n = 0; n < 4; ++n) {
            cbias[n] = bias[basecol + n * 16];
            cebon[n] = __expf(bonus[basecol + n * 16]);
        }
#pragma unroll
        for (int m = 0; m < 4; ++m) {
#pragma unroll
            for (int r = 0; r < 4; ++r) {
                const size_t rowoff = (size_t)(baserow + m * 16 + r) * 1024;
#pragma unroll
                for (int n = 0; n < 4; ++n) {
                    const size_t idx = rowoff + basecol + n * 16;
                    const float Kv  = acc[m][n][r] + cbias[n];
                    const float eK  = __expf(Kv);
                    const float ebk = cebon[n] * eK;       // exp(bonus + K)
                    const float nb  = num[idx];
                    const float db  = den[idx];
                    const float wkv = (nb + ebk * Kv) * __builtin_amdgcn_rcpf(db + ebk);
                    const float sig = eK * __builtin_amdgcn_rcpf(1.0f + eK);
                    o0[idx]  = w_decay * nb + eK * Kv;     // num_new
                    o1[idx]  = w_decay * db + eK;          // den_new
                    orw[idx] = f2bf(sig * wkv);            // rwkv (bf16 for GEMM2)
                }
            }
        }
    } else {
        float cbias[4];
#pragma unroll
        for (int n = 0; n < 4; ++n) cbias[n] = bias[basecol + n * 16];
#pragma unroll
        for (int m = 0; m < 4; ++m) {
#pragma unroll
            for (int r = 0; r < 4; ++r) {
                const size_t rowoff = (size_t)(baserow + m * 16 + r) * 1024;
#pragma unroll
                for (int n = 0; n < 4; ++n)
                    o0[rowoff + basecol + n * 16] = acc[m][n][r] + cbias[n];
            }
        }
    }
}

extern "C" void kernel_launch(void* const* d_in, const int* in_sizes, int n_in,
                              void* d_out, int out_size, void* d_ws, size_t ws_size,
                              hipStream_t stream) {
    const float* x     = (const float*)d_in[0];
    const float* xprev = (const float*)d_in[1];
    const float* num   = (const float*)d_in[2];
    const float* den   = (const float*)d_in[3];
    const float* Wk    = (const float*)d_in[4];
    const float* bk    = (const float*)d_in[5];
    const float* mixk  = (const float*)d_in[6];
    const float* Wf    = (const float*)d_in[7];
    const float* bf_   = (const float*)d_in[8];
    const float* bonus = (const float*)d_in[9];
    const float* decay = (const float*)d_in[10];

    float* out    = (float*)d_out;                      // [B, D]
    float* numnew = out + (size_t)Bsz * Dd;             // [B, DK]
    float* dennew = numnew + (size_t)Bsz * DKd;         // [B, DK]

    char* ws = (char*)d_ws;
    unsigned short* mixed = (unsigned short*)ws;                       // 32 MB
    unsigned short* WkB   = (unsigned short*)(ws + (size_t)Bsz * Dd * 2);
    unsigned short* WfB   = WkB + (size_t)DKd * Dd;                    // +2 MB
    unsigned short* rwkv  = WfB + (size_t)Dd * DKd;                    // +2 MB

    k_prep<<<2048, 256, 0, stream>>>((const float4*)x, (const float4*)xprev, mixk,
                                     (const float4*)Wk, (const float4*)Wf,
                                     mixed, WkB, WfB);

    const int grid = (Bsz / 128) * (DKd / 128);   // 1024 blocks, 2 resident/CU
    k_gemm<1><<<grid, 256, 0, stream>>>(mixed, WkB, bk, num, den, bonus, decay,
                                        numnew, dennew, rwkv);
    k_gemm<0><<<grid, 256, 0, stream>>>(rwkv, WfB, bf_, nullptr, nullptr, nullptr,
                                        nullptr, out, nullptr, nullptr);
}

// Round 7
// 184.632 us; speedup vs baseline: 1.1468x; 1.1468x over previous
//
#include <hip/hip_runtime.h>
#include <cstdint>

#define DEV static __device__ __forceinline__
#define WAITVM(N) asm volatile("s_waitcnt vmcnt(" #N ")" ::: "memory")

typedef float f32x4 __attribute__((ext_vector_type(4)));
typedef short bf16x8 __attribute__((ext_vector_type(8)));   // 8 bf16 in 4 VGPRs

constexpr int Bsz = 16384;
constexpr int Dd  = 1024;   // D
constexpr int DKd = 1024;   // DK

// float -> bf16 bits, round-to-nearest-even
DEV unsigned short f2bf(float f) {
    uint32_t u = __builtin_bit_cast(uint32_t, f);
    u += 0x7FFFu + ((u >> 16) & 1u);
    return (unsigned short)(u >> 16);
}

// async global->LDS, 16 bytes per lane (dest must be linear: base + lane*16)
DEV void async_lds16(const void* g, void* l) {
    __builtin_amdgcn_global_load_lds(
        (const __attribute__((address_space(1))) void*)g,
        (__attribute__((address_space(3))) void*)l,
        16, 0, 0);
}

// ---------------- prep (single kernel): mixed = bf16(mix*x + (1-mix)*x_prev),
// WkB = bf16(Wk), WfB = bf16(Wf) ----------------
__global__ void k_prep(const float4* __restrict__ x, const float4* __restrict__ xp,
                       const float* __restrict__ mixp,
                       const float4* __restrict__ Wk, const float4* __restrict__ Wf,
                       unsigned short* __restrict__ mixed,
                       unsigned short* __restrict__ WkB,
                       unsigned short* __restrict__ WfB) {
    constexpr int n_mix = Bsz * Dd / 4;       // 4194304
    constexpr int n_w   = DKd * Dd / 4;       // 262144
    constexpr int total = n_mix + 2 * n_w;
    const float m = *mixp, m1 = 1.0f - m;
    int i = blockIdx.x * blockDim.x + threadIdx.x;
    const int st = gridDim.x * blockDim.x;
    for (; i < total; i += st) {
        float4 a;
        unsigned short* dst;
        int idx;
        if (i < n_mix) {
            float4 xa = x[i], xb = xp[i];
            a.x = m * xa.x + m1 * xb.x;
            a.y = m * xa.y + m1 * xb.y;
            a.z = m * xa.z + m1 * xb.z;
            a.w = m * xa.w + m1 * xb.w;
            dst = mixed; idx = i;
        } else if (i < n_mix + n_w) {
            a = Wk[i - n_mix]; dst = WkB; idx = i - n_mix;
        } else {
            a = Wf[i - n_mix - n_w]; dst = WfB; idx = i - n_mix - n_w;
        }
        ushort4 o;
        o.x = f2bf(a.x); o.y = f2bf(a.y); o.z = f2bf(a.z); o.w = f2bf(a.w);
        reinterpret_cast<ushort4*>(dst)[idx] = o;
    }
}

// ---- NT GEMM, counted-vmcnt phase pipeline at 256x256 (r6 engine x r2 geometry) ----
// C[M,N] = A[M,1024] * Bw[N,1024]^T. BK=64 as 2 kk-chunks of 32; 8 waves (2x4),
// per-wave output 128x64. LDS [2buf][2kk][256*32] per operand = 128 KB, 1 block/CU.
// Phase = {32 MFMA (setprio), vmcnt(8), barrier, stage next chunk}. 3 chunks
// (12 loads/thread) in flight; vmcnt never 0 until the tail (T3+T4+T5).
// Bank swizzle: physgrp = g ^ (row&3) ^ ((row>>2)&3)  -> 2-way max (free, m136);
// same involution pre-applied on the global source, LDS linear (rule #21).
// EPI==1: RWKV epilogue; EPI==0: bias epilogue.
template <int EPI>
__global__ __launch_bounds__(512, 2)
void k_gemm(const unsigned short* __restrict__ A,   // [M,1024] bf16
            const unsigned short* __restrict__ Bw,  // [N,1024] bf16
            const float* __restrict__ bias,
            const float* __restrict__ num, const float* __restrict__ den,
            const float* __restrict__ bonus, const float* __restrict__ decayp,
            float* __restrict__ o0, float* __restrict__ o1,
            unsigned short* __restrict__ orw)
{
    __shared__ __align__(16) unsigned short As[2][2][256 * 32];  // 64 KB
    __shared__ __align__(16) unsigned short Bs[2][2][256 * 32];  // 64 KB

    const int tid = threadIdx.x;
    // r2 bijective XCD swizzle: grid 256 (64 rb x 4 cb); each XCD gets a
    // contiguous 32-wg chunk -> B fully L2-resident per XCD.
    const int bid = (int)blockIdx.x;
    const int wg  = (bid & 7) * 32 + (bid >> 3);
    const int cb  = wg & 3;
    const int rb  = wg >> 2;
    const int row0 = rb * 256;
    const int col0 = cb * 256;

    const int lane = tid & 63;
    const int wid  = tid >> 6;                      // 0..7
    const int wr = wid >> 2, wc = wid & 3;          // 2x4 wave grid: 128x64 per wave
    const int l16 = lane & 15, lq = lane >> 4;

    // ---- staging addressing (hoisted). Per chunk: 1024 16B-segs per operand;
    // thread handles segs tid and tid+512. seg -> row = seg>>2, physgrp = seg&3,
    // source logical grp = physgrp ^ (row&3) ^ ((row>>2)&3)  (same for both segs).
    const int r0   = tid >> 2;                      // 0..127
    const int glog = (tid & 3) ^ (r0 & 3) ^ ((r0 >> 2) & 3);
    const unsigned short* pa0 = A  + (size_t)(row0 + r0) * 1024 + glog * 8;
    const unsigned short* pa1 = A  + (size_t)(row0 + r0 + 128) * 1024 + glog * 8;
    const unsigned short* pb0 = Bw + (size_t)(col0 + r0) * 1024 + glog * 8;
    const unsigned short* pb1 = Bw + (size_t)(col0 + r0 + 128) * 1024 + glog * 8;

    // ---- ds_read offsets: row = base + m*16 + l16 (base mult of 64),
    // physgrp = lq ^ (l16&3) ^ ((l16>>2)&3)  (row&3 == l16&3; (row>>2)&3 == (l16>>2)&3)
    const int pg    = lq ^ (l16 & 3) ^ ((l16 >> 2) & 3);
    const int abase = (wr * 128 + l16) * 32 + pg * 8;   // + m*512
    const int bbase = (wc * 64 + l16) * 32 + pg * 8;    // + n*512

    f32x4 acc[8][4] = {};

    auto stage = [&](int buf, int kk, int t) {
        const int off = t * 64 + kk * 32;           // shorts along K
        async_lds16(pa0 + off, &As[buf][kk][tid * 8]);
        async_lds16(pa1 + off, &As[buf][kk][(tid + 512) * 8]);
        async_lds16(pb0 + off, &Bs[buf][kk][tid * 8]);
        async_lds16(pb1 + off, &Bs[buf][kk][(tid + 512) * 8]);
    };

    auto compute = [&](int buf, int kk) {
        const unsigned short* Ar = &As[buf][kk][abase];
        const unsigned short* Br = &Bs[buf][kk][bbase];
        bf16x8 af[8], bfr[4];
#pragma unroll
        for (int n = 0; n < 4; ++n)
            bfr[n] = *reinterpret_cast<const bf16x8*>(Br + n * 512);
#pragma unroll
        for (int m = 0; m < 8; ++m)
            af[m] = *reinterpret_cast<const bf16x8*>(Ar + m * 512);
        __builtin_amdgcn_s_setprio(1);
#pragma unroll
        for (int m = 0; m < 8; ++m)
#pragma unroll
            for (int n = 0; n < 4; ++n)
                acc[m][n] = __builtin_amdgcn_mfma_f32_16x16x32_bf16(
                    af[m], bfr[n], acc[m][n], 0, 0, 0);
        __builtin_amdgcn_s_setprio(0);
    };

    // prologue: chunks C0(0),C1(0),C0(1),C1(1) in flight (16 loads/thread)
    stage(0, 0, 0); stage(0, 1, 0); stage(1, 0, 1); stage(1, 1, 1);
    WAITVM(12);                                     // C0(0) resident
    __builtin_amdgcn_s_barrier();
    __builtin_amdgcn_sched_barrier(0);

#pragma unroll 1
    for (int t = 0; t < 14; ++t) {
        const int buf = t & 1;
        compute(buf, 0);
        WAITVM(8);                                  // C1(t) resident
        __builtin_amdgcn_s_barrier();
        __builtin_amdgcn_sched_barrier(0);
        stage(buf, 0, t + 2);                       // overwrite just-consumed region
        compute(buf, 1);
        WAITVM(8);                                  // C0(t+1) resident
        __builtin_amdgcn_s_barrier();
        __builtin_amdgcn_sched_barrier(0);
        stage(buf, 1, t + 2);
    }
    // t = 14 (no more staging)
    compute(0, 0);
    WAITVM(8);  __builtin_amdgcn_s_barrier(); __builtin_amdgcn_sched_barrier(0);
    compute(0, 1);
    WAITVM(4);  __builtin_amdgcn_s_barrier(); __builtin_amdgcn_sched_barrier(0);
    // t = 15
    compute(1, 0);
    WAITVM(0);  __builtin_amdgcn_s_barrier(); __builtin_amdgcn_sched_barrier(0);
    compute(1, 1);

    // ---------------- epilogue ----------------
    // C/D layout: col = lane&15, row = (lane>>4)*4 + reg  (guide §3, m89-verified)
    const int baserow = row0 + wr * 128 + lq * 4;
    const int basecol = col0 + wc * 64 + l16;

    if constexpr (EPI == 1) {
        const float w_decay = __expf(-__expf(*decayp));
        float cbias[4], cebon[4];
#pragma unroll
        for (int n = 0; n < 4; ++n) {
            cbias[n] = bias[basecol + n * 16];
            cebon[n] = __expf(bonus[basecol + n * 16]);
        }
#pragma unroll
        for (int m = 0; m < 8; ++m) {
#pragma unroll
            for (int r = 0; r < 4; ++r) {
                const size_t rowoff = (size_t)(baserow + m * 16 + r) * 1024;
#pragma unroll
                for (int n = 0; n < 4; ++n) {
                    const size_t idx = rowoff + basecol + n * 16;
                    const float Kv  = acc[m][n][r] + cbias[n];
                    const float eK  = __expf(Kv);
                    const float ebk = cebon[n] * eK;       // exp(bonus + K)
                    const float nb  = num[idx];
                    const float db  = den[idx];
                    const float wkv = (nb + ebk * Kv) * __builtin_amdgcn_rcpf(db + ebk);
                    const float sig = eK * __builtin_amdgcn_rcpf(1.0f + eK);
                    o0[idx]  = w_decay * nb + eK * Kv;     // num_new
                    o1[idx]  = w_decay * db + eK;          // den_new
                    orw[idx] = f2bf(sig * wkv);            // rwkv (bf16 for GEMM2)
                }
            }
        }
    } else {
        float cbias[4];
#pragma unroll
        for (int n = 0; n < 4; ++n) cbias[n] = bias[basecol + n * 16];
#pragma unroll
        for (int m = 0; m < 8; ++m) {
#pragma unroll
            for (int r = 0; r < 4; ++r) {
                const size_t rowoff = (size_t)(baserow + m * 16 + r) * 1024;
#pragma unroll
                for (int n = 0; n < 4; ++n)
                    o0[rowoff + basecol + n * 16] = acc[m][n][r] + cbias[n];
            }
        }
    }
}

extern "C" void kernel_launch(void* const* d_in, const int* in_sizes, int n_in,
                              void* d_out, int out_size, void* d_ws, size_t ws_size,
                              hipStream_t stream) {
    const float* x     = (const float*)d_in[0];
    const float* xprev = (const float*)d_in[1];
    const float* num   = (const float*)d_in[2];
    const float* den   = (const float*)d_in[3];
    const float* Wk    = (const float*)d_in[4];
    const float* bk    = (const float*)d_in[5];
    const float* mixk  = (const float*)d_in[6];
    const float* Wf    = (const float*)d_in[7];
    const float* bf_   = (const float*)d_in[8];
    const float* bonus = (const float*)d_in[9];
    const float* decay = (const float*)d_in[10];

    float* out    = (float*)d_out;                      // [B, D]
    float* numnew = out + (size_t)Bsz * Dd;             // [B, DK]
    float* dennew = numnew + (size_t)Bsz * DKd;         // [B, DK]

    char* ws = (char*)d_ws;
    unsigned short* mixed = (unsigned short*)ws;                       // 32 MB
    unsigned short* WkB   = (unsigned short*)(ws + (size_t)Bsz * Dd * 2);
    unsigned short* WfB   = WkB + (size_t)DKd * Dd;                    // +2 MB
    unsigned short* rwkv  = WfB + (size_t)Dd * DKd;                    // +2 MB

    k_prep<<<2048, 256, 0, stream>>>((const float4*)x, (const float4*)xprev, mixk,
                                     (const float4*)Wk, (const float4*)Wf,
                                     mixed, WkB, WfB);

    const int grid = (Bsz / 256) * (DKd / 256);   // 256 blocks, 1 per CU
    k_gemm<1><<<grid, 512, 0, stream>>>(mixed, WkB, bk, num, den, bonus, decay,
                                        numnew, dennew, rwkv);
    k_gemm<0><<<grid, 512, 0, stream>>>(rwkv, WfB, bf_, nullptr, nullptr, nullptr,
                                        nullptr, out, nullptr, nullptr);
}